// Round 6
// baseline (4341.312 us; speedup 1.0000x reference)
//
#include <hip/hip_runtime.h>
#include <hip/hip_bf16.h>
#include <cstdint>

// Problem dims
#define T_STEPS 64
#define BATCH   512
#define LDIM    1024
#define SDIM    256
#define ADIM    32
#define RDIM    512

// d_out layout (f32 elements): latents | states | means | stds | rewards
#define OFF_STATES 33554432ull            // T*B*L
#define OFF_MEANS  41943040ull            // + T*B*S
#define OFF_STDS   50331648ull
#define OFF_REW    58720256ull

#define RCHUNK 4096                       // reward MLP rows per chunk

typedef __bf16 bf16x8 __attribute__((ext_vector_type(8)));
typedef float  f32x4  __attribute__((ext_vector_type(4)));

// All operands f32 in HBM; converted to bf16 during LDS staging.
// C = [relu](A @ B^T + bias). A concat over K at K1; B/bias concat over N at N1.
struct GemmDesc {
  const float* A1;   // A rows, K-cols [0, K1)
  const float* A2;   // A K-cols [K1, K)
  int lda1, lda2, K1;
  const float* B1;   // (N1, K) row-major
  const float* B2;   // (N-N1, K) row-major
  int N1;            // must be multiple of 128 (or >= N)
  const float* bias1;
  const float* bias2;
  float* C; int ldc; int relu;
};

// Dual-GEMM: blockIdx.y < nblk1 -> g1 else g2.
// Tile 128x128, BK=32, 4 waves (2x2 of 64x64), mfma_f32_16x16x32_bf16.
__global__ __launch_bounds__(256) void k_gemm(GemmDesc g1, GemmDesc g2,
                                              int K, int nblk1) {
  const bool first = (int)blockIdx.y < nblk1;
  GemmDesc d = first ? g1 : g2;
  const int nblk = first ? blockIdx.y : (blockIdx.y - nblk1);
  const int m0 = blockIdx.x * 128;
  const int n0 = nblk * 128;

  // block-uniform B/bias source select (N1 is 128-aligned)
  const float* Bbase; const float* bp; int cofs;
  if (n0 < d.N1) { Bbase = d.B1; bp = d.bias1; cofs = 0; }
  else           { Bbase = d.B2; bp = d.bias2; cofs = d.N1; }
  const int nb0 = n0 - cofs;

  __shared__ __align__(16) __bf16 As[128][32];
  __shared__ __align__(16) __bf16 Bs[128][32];

  const int tid  = threadIdx.x;
  const int lane = tid & 63;
  const int w    = tid >> 6;
  const int wm   = w >> 1;     // 0..1
  const int wn   = w & 1;      // 0..1

  f32x4 acc[4][4];
#pragma unroll
  for (int m = 0; m < 4; ++m)
#pragma unroll
    for (int n = 0; n < 4; ++n) acc[m][n] = (f32x4){0.f, 0.f, 0.f, 0.f};

  const int lrow = lane & 15;
  const int lk   = (lane >> 4) << 3;

  for (int k0 = 0; k0 < K; k0 += 32) {
    // select A source for this K-tile (concat boundary is 32-aligned)
    const float* Asrc; int alda, ac;
    if (k0 < d.K1) { Asrc = d.A1; alda = d.lda1; ac = k0; }
    else           { Asrc = d.A2; alda = d.lda2; ac = k0 - d.K1; }

#pragma unroll
    for (int it = 0; it < 2; ++it) {
      int seg = tid + it * 256;        // 512 segments of 8 elems
      int row = seg >> 2;
      int c8  = (seg & 3) << 3;
      // A: f32 -> bf16
      const float* s = Asrc + (size_t)(m0 + row) * alda + ac + c8;
      float4 f0 = *(const float4*)s;
      float4 f1 = *(const float4*)(s + 4);
      bf16x8 va;
      va[0] = (__bf16)f0.x; va[1] = (__bf16)f0.y; va[2] = (__bf16)f0.z; va[3] = (__bf16)f0.w;
      va[4] = (__bf16)f1.x; va[5] = (__bf16)f1.y; va[6] = (__bf16)f1.z; va[7] = (__bf16)f1.w;
      *(bf16x8*)(&As[row][c8]) = va;
      // B: f32 -> bf16
      const float* bs = Bbase + (size_t)(nb0 + row) * K + k0 + c8;
      float4 g0 = *(const float4*)bs;
      float4 g1v = *(const float4*)(bs + 4);
      bf16x8 vb;
      vb[0] = (__bf16)g0.x; vb[1] = (__bf16)g0.y; vb[2] = (__bf16)g0.z; vb[3] = (__bf16)g0.w;
      vb[4] = (__bf16)g1v.x; vb[5] = (__bf16)g1v.y; vb[6] = (__bf16)g1v.z; vb[7] = (__bf16)g1v.w;
      *(bf16x8*)(&Bs[row][c8]) = vb;
    }
    __syncthreads();

    bf16x8 af[4], bfv[4];
#pragma unroll
    for (int m = 0; m < 4; ++m)
      af[m] = *(const bf16x8*)(&As[wm * 64 + m * 16 + lrow][lk]);
#pragma unroll
    for (int n = 0; n < 4; ++n)
      bfv[n] = *(const bf16x8*)(&Bs[wn * 64 + n * 16 + lrow][lk]);
#pragma unroll
    for (int m = 0; m < 4; ++m)
#pragma unroll
      for (int n = 0; n < 4; ++n)
        acc[m][n] = __builtin_amdgcn_mfma_f32_16x16x32_bf16(af[m], bfv[n], acc[m][n], 0, 0, 0);
    __syncthreads();
  }

  // epilogue: C/D layout col=lane&15, row=(lane>>4)*4+i  [m89-verified]
#pragma unroll
  for (int n = 0; n < 4; ++n) {
    int col = n0 + wn * 64 + n * 16 + (lane & 15);
    float bv = bp[col - cofs];
#pragma unroll
    for (int m = 0; m < 4; ++m) {
      int r0 = m0 + wm * 64 + m * 16 + ((lane >> 4) << 2);
#pragma unroll
      for (int i = 0; i < 4; ++i) {
        float v = acc[m][n][i] + bv;
        if (d.relu) v = fmaxf(v, 0.f);
        d.C[(size_t)(r0 + i) * d.ldc + col] = v;
      }
    }
  }
}

// GRU combine + posterior sample + output writes for step t.
// gi row: [i_r(1024) | i_z | i_n | mean(256) | std_raw(256)] (bias included)
// gh row: [h_r | h_z | h_n]
__global__ __launch_bounds__(256) void k_combine(const float* __restrict__ gi,
                                                 const float* __restrict__ gh,
                                                 const float* __restrict__ lat_prev,
                                                 const float* __restrict__ eps_t,
                                                 float* __restrict__ out, int t) {
  int idx = blockIdx.x * 256 + threadIdx.x;
  if (idx < BATCH * LDIM) {
    int b = idx >> 10, j = idx & 1023;
    const float* grow = gi + (size_t)b * 3584;
    const float* hrow = gh + (size_t)b * 3072;
    float r = 1.f / (1.f + expf(-(grow[j] + hrow[j])));
    float z = 1.f / (1.f + expf(-(grow[1024 + j] + hrow[1024 + j])));
    float n = tanhf(grow[2048 + j] + r * hrow[2048 + j]);
    float h = lat_prev[(size_t)b * LDIM + j];
    out[(size_t)t * BATCH * LDIM + idx] = (1.f - z) * n + z * h;
  } else {
    int e = idx - BATCH * LDIM;
    if (e < BATCH * SDIM) {
      int b = e >> 8, j = e & 255;
      const float* grow = gi + (size_t)b * 3584;
      float mean = grow[3072 + j];
      float sraw = grow[3328 + j];
      float sp = (sraw > 20.f) ? sraw : log1pf(expf(sraw));
      float smp = mean + sp * eps_t[e];
      size_t base = (size_t)t * BATCH * SDIM + (size_t)e;
      out[OFF_STATES + base] = smp;
      out[OFF_MEANS + base]  = mean;
      out[OFF_STDS + base]   = sp;
    }
  }
}

// reward = x2 @ w3 + b3 ; one wave per row (K=512 = 64 lanes * 8)
__global__ __launch_bounds__(256) void k_r3(const float* __restrict__ x2,
                                            const float* __restrict__ w3,
                                            const float* __restrict__ b3,
                                            float* __restrict__ out, int row0) {
  int row  = blockIdx.x * 4 + (threadIdx.x >> 6);
  int lane = threadIdx.x & 63;
  const float* xr = x2 + (size_t)row * RDIM + lane * 8;
  const float* wr = w3 + lane * 8;
  float s = 0.f;
#pragma unroll
  for (int j = 0; j < 8; ++j) s += xr[j] * wr[j];
#pragma unroll
  for (int off = 32; off > 0; off >>= 1) s += __shfl_down(s, off, 64);
  if (lane == 0) out[OFF_REW + (size_t)(row0 + row)] = s + b3[0];
}

extern "C" void kernel_launch(void* const* d_in, const int* in_sizes, int n_in,
                              void* d_out, int out_size, void* d_ws, size_t ws_size,
                              hipStream_t stream) {
  const float* prev_state  = (const float*)d_in[0];
  const float* actions     = (const float*)d_in[1];
  const float* prev_latent = (const float*)d_in[2];
  const float* eps         = (const float*)d_in[3];
  const float* W_ih = (const float*)d_in[4];
  const float* b_ih = (const float*)d_in[5];
  const float* W_hh = (const float*)d_in[6];
  const float* b_hh = (const float*)d_in[7];
  const float* W_tp = (const float*)d_in[8];
  const float* b_tp = (const float*)d_in[9];
  const float* W_po = (const float*)d_in[10];
  const float* b_po = (const float*)d_in[11];
  const float* W_r1 = (const float*)d_in[12];
  const float* b_r1 = (const float*)d_in[13];
  const float* W_r2 = (const float*)d_in[14];
  const float* b_r2 = (const float*)d_in[15];
  const float* W_r3 = (const float*)d_in[16];
  const float* b_r3 = (const float*)d_in[17];
  float* out = (float*)d_out;

  // ws layout (~32.4 MB total)
  char* p = (char*)d_ws;
  float* hidden = (float*)p; p += (size_t)512 * 1024 * 4;    // 2.00 MB
  float* gi = (float*)p;     p += (size_t)512 * 3584 * 4;    // 7.34 MB
  float* gh = (float*)p;     p += (size_t)512 * 3072 * 4;    // 6.29 MB
  float* x1 = (float*)p;     p += (size_t)RCHUNK * 512 * 4;  // 8.39 MB
  float* x2 = (float*)p;     p += (size_t)RCHUNK * 512 * 4;  // 8.39 MB

  for (int t = 0; t < T_STEPS; ++t) {
    const float* state_prev = (t == 0) ? prev_state
        : out + OFF_STATES + (size_t)(t - 1) * BATCH * SDIM;
    const float* lat_prev = (t == 0) ? prev_latent
        : out + (size_t)(t - 1) * BATCH * LDIM;

    // G1: hidden = relu([state | a_t] @ W_tp^T + b_tp)   M=512 N=1024 K=288
    GemmDesc g1{state_prev, actions + (size_t)t * BATCH * ADIM, SDIM, ADIM, SDIM,
                W_tp, W_tp, 1024, b_tp, b_tp, hidden, LDIM, 1};
    k_gemm<<<dim3(4, 8), 256, 0, stream>>>(g1, g1, SDIM + ADIM, 8);

    // G2: gi = hidden @ [W_ih;W_po]^T + [b_ih;b_po]   N=3584 (28 blocks)
    // G3: gh = lat_prev @ W_hh^T + b_hh               N=3072 (24 blocks)
    GemmDesc g2{hidden, hidden, LDIM, LDIM, LDIM,
                W_ih, W_po, 3072, b_ih, b_po, gi, 3584, 0};
    GemmDesc g3{lat_prev, lat_prev, LDIM, LDIM, LDIM,
                W_hh, W_hh, 3072, b_hh, b_hh, gh, 3072, 0};
    k_gemm<<<dim3(4, 28 + 24), 256, 0, stream>>>(g2, g3, LDIM, 28);

    k_combine<<<2560, 256, 0, stream>>>(gi, gh, lat_prev,
                                        eps + (size_t)t * BATCH * SDIM, out, t);
  }

  // reward MLP, batched over all T*B rows, chunks of RCHUNK rows
  for (int c = 0; c < (T_STEPS * BATCH) / RCHUNK; ++c) {
    size_t row0 = (size_t)c * RCHUNK;
    GemmDesc r1{out + row0 * LDIM, out + OFF_STATES + row0 * SDIM, LDIM, SDIM, LDIM,
                W_r1, W_r1, 512, b_r1, b_r1, x1, RDIM, 1};
    k_gemm<<<dim3(RCHUNK / 128, 4), 256, 0, stream>>>(r1, r1, LDIM + SDIM, 4);
    GemmDesc r2{x1, x1, RDIM, RDIM, RDIM,
                W_r2, W_r2, 512, b_r2, b_r2, x2, RDIM, 1};
    k_gemm<<<dim3(RCHUNK / 128, 4), 256, 0, stream>>>(r2, r2, RDIM, 4);
    k_r3<<<RCHUNK / 4, 256, 0, stream>>>(x2, W_r3, b_r3, out, (int)row0);
  }
}

// Round 7
// 2869.870 us; speedup vs baseline: 1.5127x; 1.5127x over previous
//
#include <hip/hip_runtime.h>
#include <hip/hip_bf16.h>
#include <cstdint>

// Problem dims
#define T_STEPS 64
#define BATCH   512
#define LDIM    1024
#define SDIM    256
#define ADIM    32
#define RDIM    512

// d_out layout (f32 elements): latents | states | means | stds | rewards
#define OFF_STATES 33554432ull            // T*B*L
#define OFF_MEANS  41943040ull            // + T*B*S
#define OFF_STDS   50331648ull
#define OFF_REW    58720256ull

#define BM 128
#define BN 64
#define BK 32

typedef __bf16 bf16x8 __attribute__((ext_vector_type(8)));
typedef __bf16 bf16x4 __attribute__((ext_vector_type(4)));
typedef float  f32x4  __attribute__((ext_vector_type(4)));

// async global->LDS, 16B per lane; LDS dest = wave-uniform base + lane*16
__device__ __forceinline__ void gload16(const void* g, void* l) {
  __builtin_amdgcn_global_load_lds(
      (const __attribute__((address_space(1))) void*)g,
      (__attribute__((address_space(3))) void*)l,
      16, 0, 0);
}

// All GEMM operands bf16. C = [relu](A @ B^T + bias).
// A concat over K at K1; B/bias concat over N at N1 (128-aligned).
// Outputs: f32 C (if non-null) and/or bf16 Cb (if non-null), both ldc.
struct GemmDesc {
  const __bf16* A1;  // A K-cols [0, K1)
  const __bf16* A2;  // A K-cols [K1, K)
  int lda1, lda2, K1;
  const __bf16* B1;  // (N1, K) row-major
  const __bf16* B2;  // rows N1.. of B
  int N1;
  const float* bias1;
  const float* bias2;
  float* C; __bf16* Cb; int ldc; int relu;
};

__global__ __launch_bounds__(256) void k_cvt4(__bf16* dst, const float* src, int n4) {
  int i = blockIdx.x * 256 + threadIdx.x;
  int stride = gridDim.x * 256;
  for (; i < n4; i += stride) {
    float4 f = ((const float4*)src)[i];
    bf16x4 v;
    v[0] = (__bf16)f.x; v[1] = (__bf16)f.y; v[2] = (__bf16)f.z; v[3] = (__bf16)f.w;
    ((bf16x4*)dst)[i] = v;
  }
}

// Dual-GEMM: blockIdx.y < nblk1 -> g1 else g2.
// Tile 128x64, BK=32, 4 waves (2x2 of 64x32), mfma_f32_16x16x32_bf16,
// global_load_lds staging, 2-phase LDS double-buffer.
__global__ __launch_bounds__(256, 2) void k_gemm(GemmDesc g1, GemmDesc g2,
                                                 int K, int nblk1) {
  const bool first = (int)blockIdx.y < nblk1;
  GemmDesc d = first ? g1 : g2;
  const int nblk = first ? blockIdx.y : (blockIdx.y - nblk1);
  const int m0 = blockIdx.x * BM;
  const int n0 = nblk * BN;

  const __bf16* Bbase; const float* bp; int cofs;
  if (n0 < d.N1) { Bbase = d.B1; bp = d.bias1; cofs = 0; }
  else           { Bbase = d.B2; bp = d.bias2; cofs = d.N1; }
  const int nb0 = n0 - cofs;

  __shared__ __align__(16) __bf16 As[2][BM][BK];   // 2 x 8 KB
  __shared__ __align__(16) __bf16 Bs[2][BN][BK];   // 2 x 4 KB

  const int tid  = threadIdx.x;
  const int lane = tid & 63;
  const int w    = tid >> 6;
  const int wm   = w >> 1;     // 0..1 -> 64 rows
  const int wn   = w & 1;      // 0..1 -> 32 cols
  const int lrow = lane & 15;
  const int lk   = (lane >> 4) << 3;

  f32x4 acc[4][2];
#pragma unroll
  for (int m = 0; m < 4; ++m)
#pragma unroll
    for (int n = 0; n < 2; ++n) acc[m][n] = (f32x4){0.f, 0.f, 0.f, 0.f};

  // staging geometry: chunk c holds LDS bytes [c*16, c*16+16) = [row=c>>2][(c&3)*8]
  const int arow = tid >> 2;          // rows 0..63 (round 0); +64 round 1
  const int acol = (tid & 3) << 3;    // elem col 0/8/16/24

  const int nt = K / BK;
  int cur = 0;

  // prologue: stage tile 0
  {
    const __bf16* Asrc; int alda, ac;
    if (0 < d.K1) { Asrc = d.A1; alda = d.lda1; ac = 0; }
    else          { Asrc = d.A2; alda = d.lda2; ac = -d.K1; }
    gload16(Asrc + (size_t)(m0 + arow) * alda + ac + acol,
            (char*)&As[0][0][0] + w * 1024);
    gload16(Asrc + (size_t)(m0 + 64 + arow) * alda + ac + acol,
            (char*)&As[0][0][0] + 4096 + w * 1024);
    gload16(Bbase + (size_t)(nb0 + arow) * K + 0 + acol,
            (char*)&Bs[0][0][0] + w * 1024);
  }
  __syncthreads();

  for (int t = 0; t < nt; ++t) {
    if (t + 1 < nt) {
      const int k0 = (t + 1) * BK;
      const __bf16* Asrc; int alda, ac;
      if (k0 < d.K1) { Asrc = d.A1; alda = d.lda1; ac = k0; }
      else           { Asrc = d.A2; alda = d.lda2; ac = k0 - d.K1; }
      char* ab = (char*)&As[cur ^ 1][0][0];
      char* bb = (char*)&Bs[cur ^ 1][0][0];
      gload16(Asrc + (size_t)(m0 + arow) * alda + ac + acol,      ab + w * 1024);
      gload16(Asrc + (size_t)(m0 + 64 + arow) * alda + ac + acol, ab + 4096 + w * 1024);
      gload16(Bbase + (size_t)(nb0 + arow) * K + k0 + acol,       bb + w * 1024);
    }

    bf16x8 af[4], bfv[2];
#pragma unroll
    for (int m = 0; m < 4; ++m)
      af[m] = *(const bf16x8*)(&As[cur][wm * 64 + m * 16 + lrow][lk]);
#pragma unroll
    for (int n = 0; n < 2; ++n)
      bfv[n] = *(const bf16x8*)(&Bs[cur][wn * 32 + n * 16 + lrow][lk]);
#pragma unroll
    for (int m = 0; m < 4; ++m)
#pragma unroll
      for (int n = 0; n < 2; ++n)
        acc[m][n] = __builtin_amdgcn_mfma_f32_16x16x32_bf16(af[m], bfv[n], acc[m][n], 0, 0, 0);

    __syncthreads();   // drains vmcnt(0)+lgkmcnt(0): next buffer staged, cur consumed
    cur ^= 1;
  }

  // epilogue: C/D layout col=lane&15, row=(lane>>4)*4+i  [m89-verified]
#pragma unroll
  for (int n = 0; n < 2; ++n) {
    int col = n0 + wn * 32 + n * 16 + lrow;
    float bv = bp[col - cofs];
#pragma unroll
    for (int m = 0; m < 4; ++m) {
      int r0 = m0 + wm * 64 + m * 16 + ((lane >> 4) << 2);
#pragma unroll
      for (int i = 0; i < 4; ++i) {
        float v = acc[m][n][i] + bv;
        if (d.relu) v = fmaxf(v, 0.f);
        if (d.C)  d.C[(size_t)(r0 + i) * d.ldc + col] = v;
        if (d.Cb) d.Cb[(size_t)(r0 + i) * d.ldc + col] = (__bf16)v;
      }
    }
  }
}

// GRU combine + posterior sample + output writes + bf16 shadows for step t.
__global__ __launch_bounds__(256) void k_combine(const float* __restrict__ gi,
                                                 const float* __restrict__ gh,
                                                 const float* __restrict__ lat_prev,
                                                 const float* __restrict__ eps_t,
                                                 float* __restrict__ out,
                                                 __bf16* __restrict__ lat_bf_next,
                                                 __bf16* __restrict__ state_bf_next,
                                                 int t) {
  int idx = blockIdx.x * 256 + threadIdx.x;
  if (idx < BATCH * LDIM) {
    int b = idx >> 10, j = idx & 1023;
    const float* grow = gi + (size_t)b * 3584;
    const float* hrow = gh + (size_t)b * 3072;
    float r = 1.f / (1.f + expf(-(grow[j] + hrow[j])));
    float z = 1.f / (1.f + expf(-(grow[1024 + j] + hrow[1024 + j])));
    float n = tanhf(grow[2048 + j] + r * hrow[2048 + j]);
    float h = lat_prev[(size_t)b * LDIM + j];
    float lat = (1.f - z) * n + z * h;
    out[(size_t)t * BATCH * LDIM + idx] = lat;
    lat_bf_next[idx] = (__bf16)lat;
  } else {
    int e = idx - BATCH * LDIM;
    if (e < BATCH * SDIM) {
      int b = e >> 8, j = e & 255;
      const float* grow = gi + (size_t)b * 3584;
      float mean = grow[3072 + j];
      float sraw = grow[3328 + j];
      float sp = (sraw > 20.f) ? sraw : log1pf(expf(sraw));
      float smp = mean + sp * eps_t[e];
      size_t base = (size_t)t * BATCH * SDIM + (size_t)e;
      out[OFF_STATES + base] = smp;
      out[OFF_MEANS + base]  = mean;
      out[OFF_STDS + base]   = sp;
      state_bf_next[e] = (__bf16)smp;
    }
  }
}

// reward = x2 @ w3 + b3 ; one wave per row (K=512 = 64 lanes * 8)
__global__ __launch_bounds__(256) void k_r3(const float* __restrict__ x2,
                                            const float* __restrict__ w3,
                                            const float* __restrict__ b3,
                                            float* __restrict__ out) {
  int row  = blockIdx.x * 4 + (threadIdx.x >> 6);
  int lane = threadIdx.x & 63;
  const float* xr = x2 + (size_t)row * RDIM + lane * 8;
  const float* wr = w3 + lane * 8;
  float s = 0.f;
#pragma unroll
  for (int j = 0; j < 8; ++j) s += xr[j] * wr[j];
#pragma unroll
  for (int off = 32; off > 0; off >>= 1) s += __shfl_down(s, off, 64);
  if (lane == 0) out[OFF_REW + (size_t)row] = s + b3[0];
}

extern "C" void kernel_launch(void* const* d_in, const int* in_sizes, int n_in,
                              void* d_out, int out_size, void* d_ws, size_t ws_size,
                              hipStream_t stream) {
  const float* prev_state  = (const float*)d_in[0];
  const float* actions     = (const float*)d_in[1];
  const float* prev_latent = (const float*)d_in[2];
  const float* eps         = (const float*)d_in[3];
  const float* W_ih = (const float*)d_in[4];
  const float* b_ih = (const float*)d_in[5];
  const float* W_hh = (const float*)d_in[6];
  const float* b_hh = (const float*)d_in[7];
  const float* W_tp = (const float*)d_in[8];
  const float* b_tp = (const float*)d_in[9];
  const float* W_po = (const float*)d_in[10];
  const float* b_po = (const float*)d_in[11];
  const float* W_r1 = (const float*)d_in[12];
  const float* b_r1 = (const float*)d_in[13];
  const float* W_r2 = (const float*)d_in[14];
  const float* b_r2 = (const float*)d_in[15];
  const float* W_r3 = (const float*)d_in[16];
  const float* b_r3 = (const float*)d_in[17];
  float* out = (float*)d_out;

  // ws layout (~218 MB; harness provides ~940 MB, fill-verified)
  char* p = (char*)d_ws;
  __bf16* Wtp_b  = (__bf16*)p; p += (size_t)1024 * 288 * 2;
  __bf16* Wih_b  = (__bf16*)p; p += (size_t)3072 * 1024 * 2;
  __bf16* Wpo_b  = (__bf16*)p; p += (size_t)512 * 1024 * 2;
  __bf16* Whh_b  = (__bf16*)p; p += (size_t)3072 * 1024 * 2;
  __bf16* Wr1_b  = (__bf16*)p; p += (size_t)512 * 1280 * 2;
  __bf16* Wr2_b  = (__bf16*)p; p += (size_t)512 * 512 * 2;
  __bf16* act_bf = (__bf16*)p; p += (size_t)T_STEPS * BATCH * ADIM * 2;
  __bf16* lat_bf = (__bf16*)p; p += (size_t)(T_STEPS + 1) * BATCH * LDIM * 2;  // slot t = latent before step t
  __bf16* state_bf = (__bf16*)p; p += (size_t)(T_STEPS + 1) * BATCH * SDIM * 2;
  __bf16* hidden_bf = (__bf16*)p; p += (size_t)BATCH * LDIM * 2;
  __bf16* x1_bf  = (__bf16*)p; p += (size_t)T_STEPS * BATCH * RDIM * 2;
  float*  gi = (float*)p; p += (size_t)BATCH * 3584 * 4;
  float*  gh = (float*)p; p += (size_t)BATCH * 3072 * 4;
  float*  x2 = (float*)p; p += (size_t)T_STEPS * BATCH * RDIM * 4;

  // per-call bf16 conversions (weights + initial state + actions)
  k_cvt4<<<1024, 256, 0, stream>>>(Wtp_b,  W_tp,  1024 * 288 / 4);
  k_cvt4<<<1024, 256, 0, stream>>>(Wih_b,  W_ih,  3072 * 1024 / 4);
  k_cvt4<<<1024, 256, 0, stream>>>(Wpo_b,  W_po,  512 * 1024 / 4);
  k_cvt4<<<1024, 256, 0, stream>>>(Whh_b,  W_hh,  3072 * 1024 / 4);
  k_cvt4<<<1024, 256, 0, stream>>>(Wr1_b,  W_r1,  512 * 1280 / 4);
  k_cvt4<<<512,  256, 0, stream>>>(Wr2_b,  W_r2,  512 * 512 / 4);
  k_cvt4<<<1024, 256, 0, stream>>>(act_bf, actions, T_STEPS * BATCH * ADIM / 4);
  k_cvt4<<<512,  256, 0, stream>>>(lat_bf, prev_latent, BATCH * LDIM / 4);
  k_cvt4<<<256,  256, 0, stream>>>(state_bf, prev_state, BATCH * SDIM / 4);

  const int BIG = 1 << 28;
  for (int t = 0; t < T_STEPS; ++t) {
    // G1: hidden_bf = relu([state|a_t] @ W_tp^T + b_tp)  M=512 N=1024 K=288
    GemmDesc g1{state_bf + (size_t)t * BATCH * SDIM, act_bf + (size_t)t * BATCH * ADIM,
                SDIM, ADIM, SDIM, Wtp_b, Wtp_b, BIG, b_tp, b_tp,
                nullptr, hidden_bf, LDIM, 1};
    k_gemm<<<dim3(4, 16), 256, 0, stream>>>(g1, g1, SDIM + ADIM, 16);

    // G2: gi = hidden @ [W_ih;W_po]^T + [b_ih;b_po]  N=3584 (56 blocks)
    // G3: gh = lat_prev @ W_hh^T + b_hh              N=3072 (48 blocks)
    GemmDesc g2{hidden_bf, hidden_bf, LDIM, LDIM, LDIM,
                Wih_b, Wpo_b, 3072, b_ih, b_po, gi, nullptr, 3584, 0};
    GemmDesc g3{lat_bf + (size_t)t * BATCH * LDIM, lat_bf + (size_t)t * BATCH * LDIM,
                LDIM, LDIM, LDIM, Whh_b, Whh_b, BIG, b_hh, b_hh,
                gh, nullptr, 3072, 0};
    k_gemm<<<dim3(4, 56 + 48), 256, 0, stream>>>(g2, g3, LDIM, 56);

    const float* lat_prev_f32 = (t == 0) ? prev_latent
        : out + (size_t)(t - 1) * BATCH * LDIM;
    k_combine<<<2560, 256, 0, stream>>>(gi, gh, lat_prev_f32,
                                        eps + (size_t)t * BATCH * SDIM, out,
                                        lat_bf + (size_t)(t + 1) * BATCH * LDIM,
                                        state_bf + (size_t)(t + 1) * BATCH * SDIM, t);
  }

  // reward MLP over all T*B = 32768 rows in one shot
  // r1: x1_bf = relu([latent|state] @ W_r1^T + b_r1)  M=32768 N=512 K=1280
  GemmDesc r1{lat_bf + (size_t)BATCH * LDIM, state_bf + (size_t)BATCH * SDIM,
              LDIM, SDIM, LDIM, Wr1_b, Wr1_b, BIG, b_r1, b_r1,
              nullptr, x1_bf, RDIM, 1};
  k_gemm<<<dim3(256, 8), 256, 0, stream>>>(r1, r1, LDIM + SDIM, 8);
  // r2: x2 = relu(x1 @ W_r2^T + b_r2)  M=32768 N=512 K=512
  GemmDesc r2{x1_bf, x1_bf, RDIM, RDIM, RDIM,
              Wr2_b, Wr2_b, BIG, b_r2, b_r2, x2, nullptr, RDIM, 1};
  k_gemm<<<dim3(256, 8), 256, 0, stream>>>(r2, r2, RDIM, 8);
  k_r3<<<T_STEPS * BATCH / 4, 256, 0, stream>>>(x2, W_r3, b_r3, out);
}